// Round 4
// baseline (834.113 us; speedup 1.0000x reference)
//
#include <hip/hip_runtime.h>

#define BB 4
#define SS 2048
#define DD 2048
#define HH 16
#define DHD 128
#define MAXL 1024

typedef __bf16 bf16x8 __attribute__((ext_vector_type(8)));
typedef float f32x4 __attribute__((ext_vector_type(4)));
typedef unsigned int u32_as1 __attribute__((address_space(1)));
typedef unsigned int u32_as3 __attribute__((address_space(3)));

__device__ __forceinline__ unsigned short f2bf(float f) {
  unsigned int u = __builtin_bit_cast(unsigned int, f);
  u += 0x7fffu + ((u >> 16) & 1u);   // RNE
  return (unsigned short)(u >> 16);
}
__device__ __forceinline__ float bf2f(unsigned short h) {
  unsigned int u = ((unsigned int)h) << 16;
  return __builtin_bit_cast(float, u);
}
union U4 { uint4 u; bf16x8 b; };
__device__ __forceinline__ bf16x8 ldfrag(const unsigned short* p) {
  U4 x; x.u = *(const uint4*)p; return x.b;
}
__device__ __forceinline__ void gl_lds16(const void* g, void* l) {
  __builtin_amdgcn_global_load_lds((const u32_as1*)g, (u32_as3*)l, 16, 0, 0);
}

// DPP 16-lane butterfly reduction (VALU pipe).
template <int C>
__device__ __forceinline__ float dppf(float x) {
  return __builtin_bit_cast(float,
      __builtin_amdgcn_mov_dpp(__builtin_bit_cast(int, x), C, 0xF, 0xF, true));
}
__device__ __forceinline__ float rmax16(float x) {
  x = fmaxf(x, dppf<0xB1>(x));
  x = fmaxf(x, dppf<0x4E>(x));
  x = fmaxf(x, dppf<0x141>(x));
  x = fmaxf(x, dppf<0x140>(x));
  return x;
}
__device__ __forceinline__ float radd16(float x) {
  x += dppf<0xB1>(x);
  x += dppf<0x4E>(x);
  x += dppf<0x141>(x);
  x += dppf<0x140>(x);
  return x;
}

// ---------------------------------------------------------------------------
__global__ void build_pos(const int* __restrict__ skip, int* __restrict__ posk,
                          int* __restrict__ nval) {
  int b = blockIdx.x, t = threadIdx.x;  // 64 threads
  __shared__ int cnts[64], offs[64];
  const int* row = skip + b * SS;
  int c = 0;
  for (int i = 0; i < 32; i++) c += (row[t * 32 + i] != 0);
  cnts[t] = c;
  __syncthreads();
  if (t == 0) {
    int run = 0;
    for (int i = 0; i < 64; i++) { offs[i] = run; run += cnts[i]; }
    nval[b] = run > MAXL ? MAXL : run;
  }
  __syncthreads();
  int o = offs[t];
  for (int i = 0; i < 32; i++)
    if (row[t * 32 + i]) { if (o < MAXL) posk[b * MAXL + o] = t * 32 + i; o++; }
  int nb = nval[b];
  for (int l = nb + t; l < MAXL; l += 64) posk[b * MAXL + l] = -1;
}

// ---------------------------------------------------------------------------
__global__ __launch_bounds__(256) void cvt3(const float* __restrict__ q,
                                            const float* __restrict__ k,
                                            const float* __restrict__ v,
                                            unsigned short* __restrict__ oq,
                                            unsigned short* __restrict__ ok,
                                            unsigned short* __restrict__ ov) {
  const int nq = BB * MAXL * DD / 4, nk = BB * SS * DD / 4;
  int idx = blockIdx.x * 256 + threadIdx.x;
  const float* src; unsigned short* dst; int off;
  if (idx < nq) { src = q; dst = oq; off = idx; }
  else if (idx < nq + nk) { src = k; dst = ok; off = idx - nq; }
  else { src = v; dst = ov; off = idx - nq - nk; }
  float4 vv = ((const float4*)src)[off];
  ushort4 h;
  h.x = f2bf(vv.x); h.y = f2bf(vv.y); h.z = f2bf(vv.z); h.w = f2bf(vv.w);
  ((ushort4*)dst)[off] = h;
}

// ---------------------------------------------------------------------------
__global__ __launch_bounds__(256) void transpose_w4(const float* __restrict__ w0,
    const float* __restrict__ w1, const float* __restrict__ w2, const float* __restrict__ w3,
    unsigned short* __restrict__ o0, unsigned short* __restrict__ o1,
    unsigned short* __restrict__ o2, unsigned short* __restrict__ o3) {
  __shared__ __align__(16) unsigned short tile[64 * 76];
  const float* W; unsigned short* Wt;
  switch (blockIdx.z) {
    case 0: W = w0; Wt = o0; break;
    case 1: W = w1; Wt = o1; break;
    case 2: W = w2; Wt = o2; break;
    default: W = w3; Wt = o3; break;
  }
  int tx = threadIdx.x;
  int K0 = blockIdx.y * 64, N0 = blockIdx.x * 64;
  #pragma unroll
  for (int i = 0; i < 4; i++) {
    int r = (tx >> 4) + i * 16, c4 = (tx & 15) * 4;
    float4 v = *(const float4*)&W[(size_t)(K0 + r) * DD + N0 + c4];
    ushort4 h;
    h.x = f2bf(v.x); h.y = f2bf(v.y); h.z = f2bf(v.z); h.w = f2bf(v.w);
    *(ushort4*)&tile[r * 76 + c4] = h;
  }
  __syncthreads();
  #pragma unroll
  for (int i = 0; i < 4; i++) {
    int n = (tx >> 4) + i * 16, k4 = (tx & 15) * 4;
    ushort4 h;
    h.x = tile[(k4 + 0) * 76 + n];
    h.y = tile[(k4 + 1) * 76 + n];
    h.z = tile[(k4 + 2) * 76 + n];
    h.w = tile[(k4 + 3) * 76 + n];
    *(ushort4*)&Wt[(size_t)(N0 + n) * DD + K0 + k4] = h;
  }
}

// ---------------------------------------------------------------------------
// 256x256 K/V-projection GEMM, fine-grained pipeline.
// Quadrant-cooperative: per K-tile, 4 phases; ALL 8 waves compute one 128x128
// C-quadrant per phase. Phase half-tile consumption: q1:{Ah0,Bh0} q2:{Bh1}
// q3:{Ah1} q4:{regs only}. Each phase stages exactly ONE half-tile of tile
// t+1 (2 gl_lds/thread), horizon 3-4 phases, vmcnt(6) steady (never 0
// mid-loop; tail 4/2/0). Frag-ordered LDS (stride-1 b128, 0 conflicts).
// WAR: every overwritten half last-read >=2 barriers before its stage-issue.
// Per-wave own ds_reads retire before trailing barrier (MFMA consumes them).
// MODE 0: head-split bf16 [b][h][l][128] (Lbits=11); MODE 2: V^T [b][h][d][S].
template <int MODE>
__global__ __launch_bounds__(512, 2) void gemm256q(const unsigned short* __restrict__ A,
                                                   const unsigned short* __restrict__ Bt,
                                                   unsigned short* __restrict__ Cb,
                                                   int K, int Lbits) {
  __shared__ __align__(16) unsigned short lds[65536];   // 128 KiB
  unsigned short* const Abuf = lds;                      // [2][32 frag][512]
  unsigned short* const Bbuf = lds + 32768;              // [2][32 frag][512]

  const int tid = threadIdx.x;
  const int lane = tid & 63, quad = lane >> 4, c = lane & 15;
  const int w = tid >> 6;
  const int wr = w >> 2, wc = w & 3;   // 2x4 wave layout inside a quadrant

  // XCD-aware block swizzle (nwg = 256, multiple of 8)
  const int nwg = gridDim.x * gridDim.y;
  const int bid0 = blockIdx.y * gridDim.x + blockIdx.x;
  const int cpx = nwg >> 3;
  const int bid = (bid0 & 7) * cpx + (bid0 >> 3);
  const int bx = bid % gridDim.x;
  const int by = bid / gridDim.x;
  const size_t tm = (size_t)by * 256, tn = (size_t)bx * 256;

  f32x4 acc[4][4][2] = {};   // [qm*2+qn][i][j]

  // stage one half: wave w stages row-group rg = half*8+w, both ks chunks.
  // frag id = rg*2+ks; LDS dst = frag base + lane*16B (linear).
  auto STG_A = [&](int sel, int tk, int half) {
    int rg = half * 8 + w;
    const unsigned short* src = A + (tm + rg * 16 + c) * (size_t)K + tk * 64 + quad * 8;
    unsigned short* dst = Abuf + sel * 16384 + (rg * 2) * 512 + lane * 8;
    gl_lds16(src, dst);
    gl_lds16(src + 32, dst + 512);
  };
  auto STG_B = [&](int sel, int tk, int half) {
    int rg = half * 8 + w;
    const unsigned short* src = Bt + (tn + rg * 16 + c) * (size_t)K + tk * 64 + quad * 8;
    unsigned short* dst = Bbuf + sel * 16384 + (rg * 2) * 512 + lane * 8;
    gl_lds16(src, dst);
    gl_lds16(src + 32, dst + 512);
  };

  const int nkt = K >> 6;
  // prologue: tile0 halves in slot order Ah0, Bh0, Bh1, Ah1 (vmcnt counting!)
  STG_A(0, 0, 0);
  STG_B(0, 0, 0);
  STG_B(0, 0, 1);
  STG_A(0, 0, 1);

  bf16x8 av[4][2], b01[2][2], b23[2][2];

#define MFMA_Q(QI, AV, BV)                                                         \
  __builtin_amdgcn_s_setprio(1);                                                   \
  _Pragma("unroll")                                                                \
  for (int i = 0; i < 4; i++)                                                      \
    _Pragma("unroll")                                                              \
    for (int j = 0; j < 2; j++)                                                    \
      _Pragma("unroll")                                                            \
      for (int ks = 0; ks < 2; ks++)                                               \
        acc[QI][i][j] = __builtin_amdgcn_mfma_f32_16x16x32_bf16(                   \
            AV[i][ks], BV[j][ks], acc[QI][i][j], 0, 0, 0);                         \
  __builtin_amdgcn_s_setprio(0);

  for (int t = 0; t < nkt; ++t) {
    const int sel = t & 1, ns = sel ^ 1;
    const unsigned short* as = Abuf + sel * 16384 + lane * 8;
    const unsigned short* bs = Bbuf + sel * 16384 + lane * 8;
    const bool more = (t + 1 < nkt);

    // ---- q1: quadrant (0,0); consumes Ah0+Bh0; stages t+1 Ah0
    if (more) { STG_A(ns, t + 1, 0); asm volatile("s_waitcnt vmcnt(6)" ::: "memory"); }
    else      {                       asm volatile("s_waitcnt vmcnt(4)" ::: "memory"); }
    __builtin_amdgcn_s_barrier();
    #pragma unroll
    for (int i = 0; i < 4; i++)
      #pragma unroll
      for (int ks = 0; ks < 2; ks++)
        av[i][ks] = ldfrag(&as[((wr * 4 + i) * 2 + ks) * 512]);
    #pragma unroll
    for (int j = 0; j < 2; j++)
      #pragma unroll
      for (int ks = 0; ks < 2; ks++)
        b01[j][ks] = ldfrag(&bs[((wc * 2 + j) * 2 + ks) * 512]);
    MFMA_Q(0, av, b01)
    __builtin_amdgcn_s_barrier();

    // ---- q2: quadrant (0,1); consumes Bh1; stages t+1 Bh0
    if (more) { STG_B(ns, t + 1, 0); asm volatile("s_waitcnt vmcnt(6)" ::: "memory"); }
    else      {                       asm volatile("s_waitcnt vmcnt(2)" ::: "memory"); }
    __builtin_amdgcn_s_barrier();
    #pragma unroll
    for (int j = 0; j < 2; j++)
      #pragma unroll
      for (int ks = 0; ks < 2; ks++)
        b23[j][ks] = ldfrag(&bs[((8 + wc * 2 + j) * 2 + ks) * 512]);
    MFMA_Q(1, av, b23)
    __builtin_amdgcn_s_barrier();

    // ---- q3: quadrant (1,0); consumes Ah1; stages t+1 Bh1
    if (more) { STG_B(ns, t + 1, 1); asm volatile("s_waitcnt vmcnt(6)" ::: "memory"); }
    else      {                       asm volatile("s_waitcnt vmcnt(0)" ::: "memory"); }
    __builtin_amdgcn_s_barrier();
    #pragma unroll
    for (int i = 0; i < 4; i++)
      #pragma unroll
      for (int ks = 0; ks < 2; ks++)
        av[i][ks] = ldfrag(&as[((8 + wr * 4 + i) * 2 + ks) * 512]);
    MFMA_Q(2, av, b01)
    __builtin_amdgcn_s_barrier();

    // ---- q4: quadrant (1,1); regs only; stages t+1 Ah1
    if (more) STG_A(ns, t + 1, 1);
    MFMA_Q(3, av, b23)
    __builtin_amdgcn_s_barrier();
  }
#undef MFMA_Q

  // ---- epilogue: staging LDS dead. Per-wave 64x32 bounce chunk (4KB).
  unsigned short* ep = lds + w * 2048;
  const size_t Lmask = ((size_t)1 << Lbits) - 1;
  #pragma unroll
  for (int qm = 0; qm < 2; qm++)
    #pragma unroll
    for (int qn = 0; qn < 2; qn++) {
      const int qi = qm * 2 + qn;
      if (MODE == 0) {
        #pragma unroll
        for (int i = 0; i < 4; i++)
          #pragma unroll
          for (int j = 0; j < 2; j++)
            #pragma unroll
            for (int r = 0; r < 4; r++)
              ep[(i * 16 + quad * 4 + r) * 32 + j * 16 + c] = f2bf(acc[qi][i][j][r]);
        #pragma unroll
        for (int it = 0; it < 4; it++) {
          int idx = it * 64 + lane;
          int row = idx >> 2, cc = (idx & 3) * 8;
          uint4 val = *(const uint4*)&ep[row * 32 + cc];
          size_t m = tm + qm * 128 + wr * 64 + row;
          size_t n = tn + qn * 128 + wc * 32 + cc;
          size_t b = m >> Lbits, l = m & Lmask, h = n >> 7, d = n & 127;
          *(uint4*)&Cb[(((b * HH + h) << Lbits) + l) * 128 + d] = val;
        }
      } else {
        // MODE 2: stage transposed [n][m], write V^T [b][h][d][S]
        #pragma unroll
        for (int i = 0; i < 4; i++)
          #pragma unroll
          for (int j = 0; j < 2; j++)
            #pragma unroll
            for (int r = 0; r < 4; r++)
              ep[(j * 16 + c) * 64 + i * 16 + quad * 4 + r] = f2bf(acc[qi][i][j][r]);
        #pragma unroll
        for (int it = 0; it < 4; it++) {
          int idx = it * 64 + lane;
          int nl = idx >> 3, mc = (idx & 7) * 8;
          uint4 val = *(const uint4*)&ep[nl * 64 + mc];
          size_t n = tn + qn * 128 + wc * 32 + nl;
          size_t m = tm + qm * 128 + wr * 64 + mc;
          size_t b = m >> 11, s = m & 2047, h = n >> 7, d = n & 127;
          *(uint4*)&Cb[((b * HH + h) * 128 + d) * SS + s] = val;
        }
      }
    }
}

// ---------------------------------------------------------------------------
// BMx256-tile bf16 GEMM (BM=128 path, used for Q and O projections).
template <int BM>
__global__ __launch_bounds__(512, 2) void gemm8(const unsigned short* __restrict__ A,
                                                const unsigned short* __restrict__ Bt,
                                                void* __restrict__ Cp,
                                                int M, int N, int K, int mode, int Lbits) {
  constexpr int AFR = BM / 8;                        // A frags per buffer
  __shared__ __align__(16) unsigned short lds[(AFR + 32) * 1024];
  unsigned short* const Abuf = lds;                  // [2][AFR*512]
  unsigned short* const Bbuf = lds + 2 * AFR * 512;  // [2][32*512]

  const int tid = threadIdx.x;
  const int lane = tid & 63, quad = lane >> 4, c = lane & 15;
  const int w = tid >> 6;
  const int wm = (w >> 2) * (BM / 2), wn = (w & 3) * 64;

  const int nwg = gridDim.x * gridDim.y;
  const int bid0 = blockIdx.y * gridDim.x + blockIdx.x;
  const int cpx = nwg >> 3;
  const int bid = (bid0 & 7) * cpx + (bid0 >> 3);
  const int bx = bid % gridDim.x;
  const int by = bid / gridDim.x;
  const size_t tm = (size_t)by * BM, tn = (size_t)bx * 256;

  constexpr int MR = BM / 32;
  f32x4 acc[MR][4] = {};

  constexpr int AN = AFR / 8;
  constexpr int NLD = AN + 4;
  const unsigned short* gA = A + (tm + c) * (size_t)K + quad * 8;
  const unsigned short* gB = Bt + (tn + c) * (size_t)K + quad * 8;

  auto STAGE = [&](int sel, int kk) {
    unsigned short* ad = Abuf + sel * (AFR * 512) + lane * 8;
    unsigned short* bd = Bbuf + sel * 16384 + lane * 8;
    #pragma unroll
    for (int n = 0; n < AN; n++) {
      int f = n * 8 + w;
      gl_lds16(gA + kk + ((size_t)(f >> 1) * 16) * K + (f & 1) * 32, ad + f * 512);
    }
    #pragma unroll
    for (int n = 0; n < 4; n++) {
      int f = n * 8 + w;
      gl_lds16(gB + kk + ((size_t)(f >> 1) * 16) * K + (f & 1) * 32, bd + f * 512);
    }
  };

  const int nkt = K >> 6;
  STAGE(0, 0);

  const int ai0 = (wm >> 4) * 2;
  const int bj0 = (wn >> 4) * 2;

  for (int t = 0; t < nkt; ++t) {
    const int sel = t & 1;
    const unsigned short* as = Abuf + sel * (AFR * 512) + lane * 8;
    const unsigned short* bs = Bbuf + sel * 16384 + lane * 8;
    if (t + 1 < nkt) {
      STAGE(sel ^ 1, (t + 1) << 6);
      asm volatile("s_waitcnt vmcnt(%0)" ::"i"(NLD) : "memory");
    } else {
      asm volatile("s_waitcnt vmcnt(0)" ::: "memory");
    }
    __builtin_amdgcn_s_barrier();

    bf16x8 a0[4][2], b01[2][2], b23[2][2];
    #pragma unroll
    for (int i = 0; i < 4; i++)
      #pragma unroll
      for (int ks = 0; ks < 2; ks++)
        a0[i][ks] = ldfrag(&as[(ai0 + i * 2 + ks) * 512]);
    #pragma unroll
    for (int j = 0; j < 2; j++)
      #pragma unroll
      for (int ks = 0; ks < 2; ks++)
        b01[j][ks] = ldfrag(&bs[(bj0 + j * 2 + ks) * 512]);
    __builtin_amdgcn_s_barrier();
    __builtin_amdgcn_s_setprio(1);
    #pragma unroll
    for (int i = 0; i < 4; i++)
      #pragma unroll
      for (int j = 0; j < 2; j++)
        #pragma unroll
        for (int ks = 0; ks < 2; ks++)
          acc[i][j] = __builtin_amdgcn_mfma_f32_16x16x32_bf16(a0[i][ks], b01[j][ks], acc[i][j], 0, 0, 0);
    __builtin_amdgcn_s_setprio(0);
    __builtin_amdgcn_s_barrier();
    #pragma unroll
    for (int j = 0; j < 2; j++)
      #pragma unroll
      for (int ks = 0; ks < 2; ks++)
        b23[j][ks] = ldfrag(&bs[(bj0 + (2 + j) * 2 + ks) * 512]);
    __builtin_amdgcn_s_barrier();
    __builtin_amdgcn_s_setprio(1);
    #pragma unroll
    for (int i = 0; i < 4; i++)
      #pragma unroll
      for (int j = 0; j < 2; j++)
        #pragma unroll
        for (int ks = 0; ks < 2; ks++)
          acc[i][2 + j] = __builtin_amdgcn_mfma_f32_16x16x32_bf16(a0[i][ks], b23[j][ks], acc[i][2 + j], 0, 0, 0);
    __builtin_amdgcn_s_setprio(0);
    __builtin_amdgcn_s_barrier();
  }

  if (mode == 1) {
    float* Cf = (float*)Cp;
    #pragma unroll
    for (int i = 0; i < MR; i++)
      #pragma unroll
      for (int j = 0; j < 4; j++)
        #pragma unroll
        for (int r = 0; r < 4; r++) {
          size_t m = tm + wm + i * 16 + quad * 4 + r;
          size_t n = tn + wn + j * 16 + c;
          Cf[m * N + n] = acc[i][j][r];
        }
    return;
  }
  unsigned short* Cb = (unsigned short*)Cp;
  unsigned short* ep = lds + w * 4352;
  const size_t Lmask = ((size_t)1 << Lbits) - 1;
  #pragma unroll
  for (int i = 0; i < 4; i++)
    #pragma unroll
    for (int j = 0; j < 4; j++)
      #pragma unroll
      for (int r = 0; r < 4; r++)
        ep[(i * 16 + quad * 4 + r) * 68 + j * 16 + c] = f2bf(acc[i][j][r]);
  #pragma unroll
  for (int it = 0; it < 8; it++) {
    int chunk = it * 64 + lane;
    int ml = chunk >> 3, nc = (chunk & 7) * 8;
    uint4 val = *(const uint4*)&ep[ml * 68 + nc];
    size_t m = tm + wm + ml, n = tn + wn + nc;
    size_t b = m >> Lbits, l = m & Lmask, h = n >> 7, d = n & 127;
    *(uint4*)&Cb[(((b * HH + h) << Lbits) + l) * 128 + d] = val;
  }
}

// ---------------------------------------------------------------------------
// fused RoPE. Q pre-scaled by 1/sqrt(128)*log2(e) (softmax runs base-2).
__global__ __launch_bounds__(256) void rope2(unsigned short* __restrict__ xq,
                                             unsigned short* __restrict__ xk,
                                             const int* __restrict__ posk) {
  constexpr float QSCL = (float)(0.08838834764831843 * 1.4426950408889634);
  const int Nq = BB * HH * MAXL * 64;
  int gid = blockIdx.x * 256 + threadIdx.x;
  unsigned short* x; int Lbits, idx, use_posk;
  if (gid < Nq) { x = xq; Lbits = 10; use_posk = 1; idx = gid; }
  else { x = xk; Lbits = 11; use_posk = 0; idx = gid - Nq; }
  int d = idx & 63;
  int rest = idx >> 6;
  int l = rest & ((1 << Lbits) - 1);
  int bh = rest >> Lbits;
  int b = bh >> 4;
  int p = use_posk ? posk[(b << 10) + l] : l;
  float ang = (float)p * __expf(-(float)d * 0.14391156831212787f); // ln(1e4)/64
  float sn, cs;
  __sincosf(ang, &sn, &cs);
  float S = use_posk ? QSCL : 1.0f;
  size_t base = (size_t)rest * 128;
  float x1 = bf2f(x[base + d]), x2 = bf2f(x[base + d + 64]);
  x[base + d]      = f2bf((x1 * cs - x2 * sn) * S);
  x[base + d + 64] = f2bf((x2 * cs + x1 * sn) * S);
}

// ---------------------------------------------------------------------------
// Flash attention: round-2 double-buffered schedule (known-good timing) with
// frag-ordered conflict-free LDS, corrected vmcnt accounting, pinned Q loads
// (so stray VMEM can't pollute the counted waits), base-2 softmax, DPP
// reduces, per-wave causal early-out, fully-visible-tile mask skip.
// LDS = 32K (K dbuf) + 32K (V^T dbuf) + 8K (P) + km -> 2 blocks/CU.
__global__ __launch_bounds__(256) void attn_kernel(const unsigned short* __restrict__ qp,
                                                   const unsigned short* __restrict__ kp,
                                                   const unsigned short* __restrict__ vtp,
                                                   const int* __restrict__ posk,
                                                   const int* __restrict__ nval,
                                                   unsigned short* __restrict__ ctx) {
  __shared__ __align__(16) unsigned short k_s[2][8192];   // 16 frags x 1KB each buf
  __shared__ __align__(16) unsigned short vt_s[2][8192];
  __shared__ __align__(16) unsigned short p_s[4096];
  __shared__ int km_s[64];

  const int tid = threadIdx.x;
  const int w = tid >> 6, lane = tid & 63, quad = lane >> 4, c = lane & 15;
  const int bh = blockIdx.x, b = bh >> 4, h = bh & 15;
  const int qbase = blockIdx.y * 64;
  const int nb = nval[b];

  if (tid < 64) {
    int l = qbase + tid;
    km_s[tid] = (l < nb) ? posk[(b << 10) + l] : -1;
  }
  __syncthreads();   // km loads complete (vmcnt waited before LDS store)

  int lv = nb - 1 - qbase; lv = lv > 63 ? 63 : lv;
  const int tile_kmax = (lv >= 0) ? km_s[lv] : -1;
  const int nkt = (tile_kmax >= 0) ? ((tile_kmax >> 6) + 1) : 0;
  const bool whas = (w * 16 <= lv);
  int wl = w * 16 + 15; if (wl > lv) wl = lv;
  const int wkmax = whas ? km_s[wl] : -1;
  const int kminw = whas ? km_s[w * 16] : -1;
  int km[4];
  #pragma unroll
  for (int r = 0; r < 4; r++) km[r] = km_s[w * 16 + quad * 4 + r];

  // Q fragments in registers; pin so their VMEM completes before staging
  const unsigned short* qg = qp + (((size_t)bh << 10) + qbase) * 128;
  bf16x8 aq[4];
  #pragma unroll
  for (int ks = 0; ks < 4; ks++)
    aq[ks] = ldfrag(&qg[(size_t)(w * 16 + c) * 128 + ks * 32 + quad * 8]);
  asm volatile("" : "+v"(aq[0]), "+v"(aq[1]), "+v"(aq[2]), "+v"(aq[3]) :: "memory");

  // frag-ordered staging pointers
  const unsigned short* kgp = kp + ((size_t)bh * SS + c) * 128 + (w * 4 + quad) * 8;
  auto STG = [&](int buf, int kb) {
    #pragma unroll
    for (int n = 0; n < 4; n++)   // K frags fid=n*4+w: key-rg n, d-chunk w
      gl_lds16(kgp + (size_t)(kb + n * 16) * 128, &k_s[buf][(n * 4 + w) * 512 + lane * 8]);
    #pragma unroll
    for (int n = 0; n < 4; n++) { // V frags fid=n*4+w: d-rg fid>>1, s-chunk fid&1
      int f = n * 4 + w;
      gl_lds16(vtp + ((size_t)bh * 128 + (f >> 1) * 16 + c) * SS + kb + ((f & 1) * 4 + quad) * 8,
               &vt_s[buf][f * 512 + lane * 8]);
    }
  };

  float m_i[4], l_i[4];
  #pragma unroll
  for (int r = 0; r < 4; r++) { m_i[r] = -1e30f; l_i[r] = 0.f; }
  f32x4 o[8];
  #pragma unroll
  for (int dj = 0; dj < 8; dj++) o[dj] = (f32x4){0.f, 0.f, 0.f, 0.f};

  const int pwb = w * 1024 + quad * 32 + (c & 7) + (c >> 3) * 128;

  if (nkt > 0) STG(0, 0);

  for (int kt = 0; kt < nkt; kt++) {
    const int cur = kt & 1;
    const int kb = kt * 64;
    if (kt + 1 < nkt) {
      STG(cur ^ 1, kb + 64);   // 8 new in flight; 8 older = tile kt
      asm volatile("s_waitcnt vmcnt(8)" ::: "memory");   // tile kt landed
    } else {
      asm volatile("s_waitcnt vmcnt(0)" ::: "memory");
    }
    __builtin_amdgcn_s_barrier();   // tile kt visible block-wide

    if (kb <= wkmax) {   // wave-uniform causal early-out
      f32x4 sa[4];
      #pragma unroll
      for (int j = 0; j < 4; j++) {
        sa[j] = (f32x4){0.f, 0.f, 0.f, 0.f};
        #pragma unroll
        for (int ks = 0; ks < 4; ks++) {
          bf16x8 bk = ldfrag(&k_s[cur][(j * 4 + ks) * 512 + lane * 8]);
          sa[j] = __builtin_amdgcn_mfma_f32_16x16x32_bf16(aq[ks], bk, sa[j], 0, 0, 0);
        }
      }

      // online softmax, base-2
      float mt[4] = {-1e30f, -1e30f, -1e30f, -1e30f};
      if (kb + 63 <= kminw) {
        #pragma unroll
        for (int j = 0; j < 4; j++)
          #pragma unroll
          for (int r = 0; r < 4; r++) mt[r] = fmaxf(mt[r], sa[j][r]);
      } else {
        #pragma unroll
        for (int j = 0; j < 4; j++) {
          int key = kb + j * 16 + c;
          #pragma unroll
          for (int r = 0; r < 4; r++) {
            float v = (key <= km[r]) ? sa[j][r] : -1e30f;
            sa[j][r] = v;
            mt[r] = fmaxf(mt[r], v);
          }
        }
      }
      float al[4], rs[4];
      #pragma unroll
      for (int r = 0; r < 4; r++) {
        mt[r] = rmax16(mt[r]);
        float mn = fmaxf(m_i[r], mt[r]);
        al[r] = __builtin_exp2f(m_i[r] - mn);
        m_i[r] = mn;
        rs[r] = 0.f;
      }
      #pragma unroll
      for (int j = 0; j < 4; j++)
        #pragma unroll
        for (int r = 0; r < 4; r++) {
          float pv = __builtin_exp2f(sa[j][r] - m_i[r]);
          sa[j][r] = pv;
          rs[r] += pv;
        }
      #pragma unroll
      for (int r = 0; r < 4; r++) {
        rs[r] = radd16(rs[r]);
        l_i[r] = l_i[r] * al[r] + rs[r];
      }
      #pragma unroll
      for (int dj = 0; dj < 8; dj++)
        #pragma unroll
        for (int r = 0; r < 4; r++) o[dj][r] *= al[r];

      // P -> frag-ordered LDS -> A-layout (per-wave region)
      #pragma unroll
      for (int j = 0; j < 4; j++)
        #pragma unroll
        for (int r = 0; r < 4; r++)
          p_s[pwb + (j >> 1) * 512 + (j & 1) * 256 + r * 8] = f2bf(sa[j][r]);
      #pragma unroll
      for (int ks2 = 0; ks2 < 2; ks2++) {
        bf16x8 ap = ldfrag(&p_s[(w * 2 + ks2) * 512 + lane * 8]);
        #pragma unroll
        for (int dj = 0; dj < 8; dj++) {
          bf16x8 bv = ldfrag(&vt_s[cur][(dj * 2 + ks2) * 512 + lane * 8]);
          o[dj] = __builtin_amdgcn_mfma_f32_16x16x32_bf16(ap, bv, o[dj], 0, 0, 0);
        }
      }
    }
    __builtin_amdgcn_s_barrier();   // buf[cur] reads retired before overwrite
  }

  #pragma unroll
  for (int r = 0; r < 4; r++) {
    int l = qbase + w * 16 + quad * 4 + r;
    bool ok = (l < nb);
    float inv = ok ? (1.0f / l_i[r]) : 0.0f;
    #pragma unroll
    for (int dj = 0; dj < 8; dj++)
      ctx[(((size_t)b << 10) + l) * (size_t)DD + h * 128 + dj * 16 + c] =
          f2bf(ok ? o[dj][r] * inv : 0.0f);
  }
}

// ---------------------------------------------------------------------------
extern "C" void kernel_launch(void* const* d_in, const int* in_sizes, int n_in,
                              void* d_out, int out_size, void* d_ws, size_t ws_size,
                              hipStream_t stream) {
  const float* q_src = (const float*)d_in[0];
  const float* k_src = (const float*)d_in[1];
  const float* v_src = (const float*)d_in[2];
  const float* Wq = (const float*)d_in[3];
  const float* Wk = (const float*)d_in[4];
  const float* Wv = (const float*)d_in[5];
  const float* Wo = (const float*)d_in[6];
  const int* skip = (const int*)d_in[9];

  char* p = (char*)d_ws;
  auto alloc = [&](size_t bytes) -> char* {
    char* r = p;
    p += (bytes + 255) & ~(size_t)255;
    return r;
  };
  unsigned short* a_q  = (unsigned short*)alloc((size_t)BB * MAXL * DD * 2);
  unsigned short* a_k  = (unsigned short*)alloc((size_t)BB * SS * DD * 2);
  unsigned short* a_v  = (unsigned short*)alloc((size_t)BB * SS * DD * 2);
  unsigned short* wt_q = (unsigned short*)alloc((size_t)DD * DD * 2);
  unsigned short* wt_k = (unsigned short*)alloc((size_t)DD * DD * 2);
  unsigned short* wt_v = (unsigned short*)alloc((size_t)DD * DD * 2);
  unsigned short* wt_o = (unsigned short*)alloc((size_t)DD * DD * 2);
  unsigned short* q_pro = (unsigned short*)alloc((size_t)BB * HH * MAXL * DHD * 2);
  unsigned short* k_pro = (unsigned short*)alloc((size_t)BB * HH * SS * DHD * 2);
  unsigned short* v_t   = (unsigned short*)alloc((size_t)BB * HH * SS * DHD * 2);
  int* posk = (int*)alloc((size_t)BB * MAXL * 4);
  int* nval = (int*)alloc(64);
  unsigned short* ctx = a_q;  // a_q dead after Q projection

  build_pos<<<BB, 64, 0, stream>>>(skip, posk, nval);
  cvt3<<<(BB * MAXL * DD + 2 * BB * SS * DD) / (4 * 256), 256, 0, stream>>>(
      q_src, k_src, v_src, a_q, a_k, a_v);
  transpose_w4<<<dim3(32, 32, 4), 256, 0, stream>>>(Wq, Wk, Wv, Wo, wt_q, wt_k, wt_v, wt_o);

  gemm8<128><<<dim3(8, 32), 512, 0, stream>>>(a_q, wt_q, q_pro, BB * MAXL, DD, DD, 0, 10);
  gemm256q<0><<<dim3(8, 32), 512, 0, stream>>>(a_k, wt_k, k_pro, DD, 11);
  gemm256q<2><<<dim3(8, 32), 512, 0, stream>>>(a_v, wt_v, v_t, DD, 11);

  rope2<<<(BB * HH * (MAXL + SS) * 64) / 256, 256, 0, stream>>>(q_pro, k_pro, posk);

  attn_kernel<<<dim3(BB * HH, MAXL / 64), 256, 0, stream>>>(q_pro, k_pro, v_t, posk, nval, ctx);

  gemm8<128><<<dim3(8, 32), 512, 0, stream>>>(ctx, wt_o, d_out, BB * MAXL, DD, DD, 1, 0);
}

// Round 5
// 709.551 us; speedup vs baseline: 1.1755x; 1.1755x over previous
//
#include <hip/hip_runtime.h>

#define BB 4
#define SS 2048
#define DD 2048
#define HH 16
#define DHD 128
#define MAXL 1024

typedef __bf16 bf16x8 __attribute__((ext_vector_type(8)));
typedef float f32x4 __attribute__((ext_vector_type(4)));
typedef unsigned int u32_as1 __attribute__((address_space(1)));
typedef unsigned int u32_as3 __attribute__((address_space(3)));

__device__ __forceinline__ unsigned short f2bf(float f) {
  unsigned int u = __builtin_bit_cast(unsigned int, f);
  u += 0x7fffu + ((u >> 16) & 1u);   // RNE
  return (unsigned short)(u >> 16);
}
__device__ __forceinline__ float bf2f(unsigned short h) {
  unsigned int u = ((unsigned int)h) << 16;
  return __builtin_bit_cast(float, u);
}
union U4 { uint4 u; bf16x8 b; };
__device__ __forceinline__ bf16x8 ldfrag(const unsigned short* p) {
  U4 x; x.u = *(const uint4*)p; return x.b;
}
__device__ __forceinline__ void gl_lds16(const void* g, void* l) {
  __builtin_amdgcn_global_load_lds((const u32_as1*)g, (u32_as3*)l, 16, 0, 0);
}

// DPP 16-lane butterfly reduction (VALU pipe).
template <int C>
__device__ __forceinline__ float dppf(float x) {
  return __builtin_bit_cast(float,
      __builtin_amdgcn_mov_dpp(__builtin_bit_cast(int, x), C, 0xF, 0xF, true));
}
__device__ __forceinline__ float rmax16(float x) {
  x = fmaxf(x, dppf<0xB1>(x));
  x = fmaxf(x, dppf<0x4E>(x));
  x = fmaxf(x, dppf<0x141>(x));
  x = fmaxf(x, dppf<0x140>(x));
  return x;
}
__device__ __forceinline__ float radd16(float x) {
  x += dppf<0xB1>(x);
  x += dppf<0x4E>(x);
  x += dppf<0x141>(x);
  x += dppf<0x140>(x);
  return x;
}

// ---------------------------------------------------------------------------
// Fused preprocessing: blocks [0, NCVT) fp32->bf16 convert of q/k/v sources;
// [NCVT, NCVT+NTW) weight transpose (4 matrices); [NCVT+NTW, +4) build_pos.
// Branch is block-uniform; __syncthreads only inside a uniform branch.
#define NCVT 40960   // (BB*MAXL*DD + 2*BB*SS*DD) / (4*256)
#define NTW  4096    // 32*32*4
__global__ __launch_bounds__(256) void prep(
    const float* __restrict__ q, const float* __restrict__ k, const float* __restrict__ v,
    unsigned short* __restrict__ oq, unsigned short* __restrict__ ok,
    unsigned short* __restrict__ ov,
    const float* __restrict__ w0, const float* __restrict__ w1,
    const float* __restrict__ w2, const float* __restrict__ w3,
    unsigned short* __restrict__ t0, unsigned short* __restrict__ t1,
    unsigned short* __restrict__ t2, unsigned short* __restrict__ t3,
    const int* __restrict__ skip, int* __restrict__ posk, int* __restrict__ nval) {
  __shared__ __align__(16) unsigned short tile[64 * 76];
  __shared__ int cnts[64], offs[64];
  const int bid = blockIdx.x;
  const int tx = threadIdx.x;

  if (bid < NCVT) {
    // ---- cvt3
    const int nq = BB * MAXL * DD / 4, nk = BB * SS * DD / 4;
    int idx = bid * 256 + tx;
    const float* src; unsigned short* dst; int off;
    if (idx < nq) { src = q; dst = oq; off = idx; }
    else if (idx < nq + nk) { src = k; dst = ok; off = idx - nq; }
    else { src = v; dst = ov; off = idx - nq - nk; }
    float4 vv = ((const float4*)src)[off];
    ushort4 hh;
    hh.x = f2bf(vv.x); hh.y = f2bf(vv.y); hh.z = f2bf(vv.z); hh.w = f2bf(vv.w);
    ((ushort4*)dst)[off] = hh;
  } else if (bid < NCVT + NTW) {
    // ---- transpose_w4
    int rem = bid - NCVT;
    int z = rem >> 10, r2 = rem & 1023;
    int bx = r2 & 31, by = r2 >> 5;
    const float* W; unsigned short* Wt;
    switch (z) {
      case 0: W = w0; Wt = t0; break;
      case 1: W = w1; Wt = t1; break;
      case 2: W = w2; Wt = t2; break;
      default: W = w3; Wt = t3; break;
    }
    int K0 = by * 64, N0 = bx * 64;
    #pragma unroll
    for (int i = 0; i < 4; i++) {
      int r = (tx >> 4) + i * 16, c4 = (tx & 15) * 4;
      float4 vv = *(const float4*)&W[(size_t)(K0 + r) * DD + N0 + c4];
      ushort4 hh;
      hh.x = f2bf(vv.x); hh.y = f2bf(vv.y); hh.z = f2bf(vv.z); hh.w = f2bf(vv.w);
      *(ushort4*)&tile[r * 76 + c4] = hh;
    }
    __syncthreads();
    #pragma unroll
    for (int i = 0; i < 4; i++) {
      int n = (tx >> 4) + i * 16, k4 = (tx & 15) * 4;
      ushort4 hh;
      hh.x = tile[(k4 + 0) * 76 + n];
      hh.y = tile[(k4 + 1) * 76 + n];
      hh.z = tile[(k4 + 2) * 76 + n];
      hh.w = tile[(k4 + 3) * 76 + n];
      *(ushort4*)&Wt[(size_t)(N0 + n) * DD + K0 + k4] = hh;
    }
  } else {
    // ---- build_pos (256 threads, work on t<64)
    int b = bid - (NCVT + NTW);
    const int* row = skip + b * SS;
    if (tx < 64) {
      int c = 0;
      for (int i = 0; i < 32; i++) c += (row[tx * 32 + i] != 0);
      cnts[tx] = c;
    }
    __syncthreads();
    if (tx == 0) {
      int run = 0;
      for (int i = 0; i < 64; i++) { offs[i] = run; run += cnts[i]; }
      nval[b] = run > MAXL ? MAXL : run;
    }
    __syncthreads();
    if (tx < 64) {
      int o = offs[tx];
      for (int i = 0; i < 32; i++)
        if (row[tx * 32 + i]) { if (o < MAXL) posk[b * MAXL + o] = tx * 32 + i; o++; }
      int nb = nval[b];
      for (int l = nb + tx; l < MAXL; l += 64) posk[b * MAXL + l] = -1;
    }
  }
}

// ---------------------------------------------------------------------------
// BMx256-tile bf16 GEMM (round-1 verbatim: row-major LDS with in-row XOR
// swizzle -> fully coalesced global_load_lds staging), BK=64, 512 threads
// (8 waves, 2M x 4N). Double-buffered, counted vmcnt, raw s_barrier phases.
// mode 0: head-split bf16 [b][h][l][128]; mode 1: fp32 [M][N]; mode 2: V^T.
template <int BM>
__global__ __launch_bounds__(512, 2) void gemm8(const unsigned short* __restrict__ A,
                                                const unsigned short* __restrict__ Bt,
                                                void* __restrict__ Cp,
                                                int M, int N, int K, int mode, int Lbits) {
  constexpr int AW = BM * 64;                  // ushorts per A buffer
  __shared__ __align__(16) unsigned short lds[(BM + 256) * 64 * 2];
  unsigned short* const Abuf = lds;            // [2][BM][64]
  unsigned short* const Bbuf = lds + 2 * AW;   // [2][256][64]

  const int tid = threadIdx.x;
  const int lane = tid & 63, quad = lane >> 4, c = lane & 15;
  const int w = tid >> 6;
  const int wm = (w >> 2) * (BM / 2), wn = (w & 3) * 64;

  const int nwg = gridDim.x * gridDim.y;
  const int bid0 = blockIdx.y * gridDim.x + blockIdx.x;
  const int cpx = nwg >> 3;
  const int bid = (bid0 & 7) * cpx + (bid0 >> 3);
  const int bx = bid % gridDim.x;
  const int by = bid / gridDim.x;
  const size_t tm = (size_t)by * BM, tn = (size_t)bx * 256;

  constexpr int MR = BM / 32;
  f32x4 acc[MR][4] = {};

  const int trow = tid >> 3;
  const int tch = ((tid & 7) ^ (trow & 7)) * 8;
  const unsigned short* gA = A + (tm + trow) * (size_t)K + tch;
  const unsigned short* gB = Bt + (tn + trow) * (size_t)K + tch;
  constexpr int ALD = BM / 64;
  constexpr int NLD = ALD + 4;

  auto STAGE = [&](int sel, int kk) {
    unsigned short* ad = Abuf + sel * AW;
    unsigned short* bd = Bbuf + sel * 16384;
    #pragma unroll
    for (int i = 0; i < ALD; i++)
      gl_lds16(gA + kk + (size_t)(i * 64) * K, ad + i * 4096 + tid * 8);
    #pragma unroll
    for (int i = 0; i < 4; i++)
      gl_lds16(gB + kk + (size_t)(i * 64) * K, bd + i * 4096 + tid * 8);
  };

  const int nkt = K >> 6;
  STAGE(0, 0);

  for (int t = 0; t < nkt; ++t) {
    const int sel = t & 1;
    const unsigned short* as = Abuf + sel * AW;
    const unsigned short* bs = Bbuf + sel * 16384;
    if (t + 1 < nkt) {
      STAGE(sel ^ 1, (t + 1) << 6);
      asm volatile("s_waitcnt vmcnt(%0)" ::"i"(NLD) : "memory");
    } else {
      asm volatile("s_waitcnt vmcnt(0)" ::: "memory");
    }
    __builtin_amdgcn_s_barrier();

    bf16x8 a0[4][2], b01[2][2], b23[2][2];
    // ---- P1
    #pragma unroll
    for (int i = 0; i < 4; i++)
      #pragma unroll
      for (int ks = 0; ks < 2; ks++)
        a0[i][ks] = ldfrag(&as[(wm + i * 16 + c) * 64 + (((ks * 4 + quad) ^ (c & 7)) << 3)]);
    #pragma unroll
    for (int j = 0; j < 2; j++)
      #pragma unroll
      for (int ks = 0; ks < 2; ks++)
        b01[j][ks] = ldfrag(&bs[(wn + j * 16 + c) * 64 + (((ks * 4 + quad) ^ (c & 7)) << 3)]);
    __builtin_amdgcn_s_barrier();
    __builtin_amdgcn_s_setprio(1);
    #pragma unroll
    for (int i = 0; i < 4; i++)
      #pragma unroll
      for (int j = 0; j < 2; j++)
        #pragma unroll
        for (int ks = 0; ks < 2; ks++)
          acc[i][j] = __builtin_amdgcn_mfma_f32_16x16x32_bf16(a0[i][ks], b01[j][ks], acc[i][j], 0, 0, 0);
    __builtin_amdgcn_s_setprio(0);
    __builtin_amdgcn_s_barrier();
    // ---- P2
    #pragma unroll
    for (int j = 0; j < 2; j++)
      #pragma unroll
      for (int ks = 0; ks < 2; ks++)
        b23[j][ks] = ldfrag(&bs[(wn + 32 + j * 16 + c) * 64 + (((ks * 4 + quad) ^ (c & 7)) << 3)]);
    __builtin_amdgcn_s_barrier();
    __builtin_amdgcn_s_setprio(1);
    #pragma unroll
    for (int i = 0; i < 4; i++)
      #pragma unroll
      for (int ks = 0; ks < 2; ks++)
        #pragma unroll
        for (int j = 0; j < 2; j++)
          acc[i][2 + j] = __builtin_amdgcn_mfma_f32_16x16x32_bf16(a0[i][ks], b23[j][ks], acc[i][2 + j], 0, 0, 0);
    __builtin_amdgcn_s_setprio(0);
    __builtin_amdgcn_s_barrier();

    if constexpr (BM == 256) {
      // ---- P3
      bf16x8 a1[4][2];
      #pragma unroll
      for (int i = 0; i < 4; i++)
        #pragma unroll
        for (int ks = 0; ks < 2; ks++)
          a1[i][ks] = ldfrag(&as[(wm + 64 + i * 16 + c) * 64 + (((ks * 4 + quad) ^ (c & 7)) << 3)]);
      __builtin_amdgcn_s_barrier();
      __builtin_amdgcn_s_setprio(1);
      #pragma unroll
      for (int i = 0; i < 4; i++)
        #pragma unroll
        for (int j = 0; j < 2; j++)
          #pragma unroll
          for (int ks = 0; ks < 2; ks++)
            acc[4 + i][j] = __builtin_amdgcn_mfma_f32_16x16x32_bf16(a1[i][ks], b01[j][ks], acc[4 + i][j], 0, 0, 0);
      __builtin_amdgcn_s_setprio(0);
      __builtin_amdgcn_s_barrier();
      // ---- P4
      __builtin_amdgcn_s_setprio(1);
      #pragma unroll
      for (int i = 0; i < 4; i++)
        #pragma unroll
        for (int j = 0; j < 2; j++)
          #pragma unroll
          for (int ks = 0; ks < 2; ks++)
            acc[4 + i][2 + j] = __builtin_amdgcn_mfma_f32_16x16x32_bf16(a1[i][ks], b23[j][ks], acc[4 + i][2 + j], 0, 0, 0);
      __builtin_amdgcn_s_setprio(0);
      __builtin_amdgcn_s_barrier();
    }
  }

  // ---- epilogue
  if (mode == 1) {
    float* Cf = (float*)Cp;
    #pragma unroll
    for (int i = 0; i < MR; i++)
      #pragma unroll
      for (int j = 0; j < 4; j++)
        #pragma unroll
        for (int r = 0; r < 4; r++) {
          size_t m = tm + wm + i * 16 + quad * 4 + r;
          size_t n = tn + wn + j * 16 + c;
          Cf[m * N + n] = acc[i][j][r];
        }
    return;
  }
  unsigned short* Cb = (unsigned short*)Cp;
  unsigned short* ep = lds + w * 4352;   // per-wave [64][68] bounce tile
  constexpr int MH = BM / 128;
  if (mode == 0) {
    const size_t Lmask = ((size_t)1 << Lbits) - 1;
    #pragma unroll
    for (int mh = 0; mh < MH; mh++) {
      #pragma unroll
      for (int i = 0; i < 4; i++)
        #pragma unroll
        for (int j = 0; j < 4; j++)
          #pragma unroll
          for (int r = 0; r < 4; r++)
            ep[(i * 16 + quad * 4 + r) * 68 + j * 16 + c] = f2bf(acc[mh * 4 + i][j][r]);
      #pragma unroll
      for (int it = 0; it < 8; it++) {
        int chunk = it * 64 + lane;
        int ml = chunk >> 3, nc = (chunk & 7) * 8;
        uint4 val = *(const uint4*)&ep[ml * 68 + nc];
        size_t m = tm + wm + mh * 64 + ml, n = tn + wn + nc;
        size_t b = m >> Lbits, l = m & Lmask, h = n >> 7, d = n & 127;
        *(uint4*)&Cb[(((b * HH + h) << Lbits) + l) * 128 + d] = val;
      }
    }
  } else {
    #pragma unroll
    for (int mh = 0; mh < MH; mh++) {
      #pragma unroll
      for (int i = 0; i < 4; i++)
        #pragma unroll
        for (int j = 0; j < 4; j++)
          #pragma unroll
          for (int r = 0; r < 4; r++)
            ep[(j * 16 + c) * 68 + i * 16 + quad * 4 + r] = f2bf(acc[mh * 4 + i][j][r]);
      #pragma unroll
      for (int it = 0; it < 8; it++) {
        int chunk = it * 64 + lane;
        int nl = chunk >> 3, mc = (chunk & 7) * 8;
        uint4 val = *(const uint4*)&ep[nl * 68 + mc];
        size_t n = tn + wn + nl, m = tm + wm + mh * 64 + mc;
        size_t b = m >> 11, s = m & 2047, h = n >> 7, d = n & 127;
        *(uint4*)&Cb[((b * HH + h) * 128 + d) * SS + s] = val;
      }
    }
  }
}

// ---------------------------------------------------------------------------
// fused RoPE. Q pre-scaled by 1/sqrt(128)*log2(e) (softmax runs base-2).
__global__ __launch_bounds__(256) void rope2(unsigned short* __restrict__ xq,
                                             unsigned short* __restrict__ xk,
                                             const int* __restrict__ posk) {
  constexpr float QSCL = (float)(0.08838834764831843 * 1.4426950408889634);
  const int Nq = BB * HH * MAXL * 64;
  int gid = blockIdx.x * 256 + threadIdx.x;
  unsigned short* x; int Lbits, idx, use_posk;
  if (gid < Nq) { x = xq; Lbits = 10; use_posk = 1; idx = gid; }
  else { x = xk; Lbits = 11; use_posk = 0; idx = gid - Nq; }
  int d = idx & 63;
  int rest = idx >> 6;
  int l = rest & ((1 << Lbits) - 1);
  int bh = rest >> Lbits;
  int b = bh >> 4;
  int p = use_posk ? posk[(b << 10) + l] : l;
  float ang = (float)p * __expf(-(float)d * 0.14391156831212787f); // ln(1e4)/64
  float sn, cs;
  __sincosf(ang, &sn, &cs);
  float S = use_posk ? QSCL : 1.0f;
  size_t base = (size_t)rest * 128;
  float x1 = bf2f(x[base + d]), x2 = bf2f(x[base + d + 64]);
  x[base + d]      = f2bf((x1 * cs - x2 * sn) * S);
  x[base + d + 64] = f2bf((x2 * cs + x1 * sn) * S);
}

// ---------------------------------------------------------------------------
// Flash attention, round-1 schedule (measured 118 us) with TWO q-strips (128
// rows) per block: K/V staging per tile unchanged but amortized over 2x MFMA;
// total staging work across the grid halves. Double-buffered K/V via
// global_load_lds (row-XOR swizzled source, coalesced), counted vmcnt(8)
// (never 0 mid-loop), raw s_barrier. DPP softmax reduces, base-2 exp
// (Q pre-scaled in rope2), per-strip wave-uniform causal early-out,
// fully-visible-tile mask skip. Q loads pinned so vmcnt counts are exact.
// Grid: (bh 64, qtile 8) — bh fastest: all q-tiles of one bh share an XCD L2.
__global__ __launch_bounds__(256) void attn_kernel(const unsigned short* __restrict__ qp,
                                                   const unsigned short* __restrict__ kp,
                                                   const unsigned short* __restrict__ vtp,
                                                   const int* __restrict__ posk,
                                                   const int* __restrict__ nval,
                                                   unsigned short* __restrict__ ctx) {
  __shared__ __align__(16) unsigned short k_s[2][64 * 128];   // [s][d] swizzled
  __shared__ __align__(16) unsigned short vt_s[2][128 * 64];  // [d][s] swizzled
  __shared__ __align__(16) unsigned short p_s[4 * 16 * 72];
  __shared__ int km_s[128];

  const int tid = threadIdx.x;
  const int w = tid >> 6, lane = tid & 63, quad = lane >> 4, c = lane & 15;
  const int bh = blockIdx.x, b = bh >> 4, h = bh & 15;
  const int qbase = blockIdx.y << 7;   // 128 rows per block
  const int nb = nval[b];

  if (tid < 128) {
    int l = qbase + tid;
    km_s[tid] = (l < nb) ? posk[(b << 10) + l] : -1;
  }
  __syncthreads();

  int lv = nb - 1 - qbase; lv = lv > 127 ? 127 : lv;
  const int nkt = (lv >= 0) ? ((km_s[lv] >> 6) + 1) : 0;

  int wkx[2], kmn[2], km[2][4];
  #pragma unroll
  for (int s = 0; s < 2; s++) {
    int bs = s * 64 + w * 16;
    bool whas = (bs <= lv);
    int wl = bs + 15; if (wl > lv) wl = lv;
    wkx[s] = whas ? km_s[wl] : -1;
    kmn[s] = whas ? km_s[bs] : -1;
    #pragma unroll
    for (int r = 0; r < 4; r++) km[s][r] = km_s[bs + quad * 4 + r];
  }

  // Q fragments in registers, both strips; pin so vmcnt accounting is exact
  const unsigned short* qg = qp + ((size_t)bh << 10) * 128;
  bf16x8 aq[2][4];
  #pragma unroll
  for (int s = 0; s < 2; s++)
    #pragma unroll
    for (int ks = 0; ks < 4; ks++)
      aq[s][ks] = ldfrag(&qg[(size_t)(qbase + s * 64 + w * 16 + c) * 128 + ks * 32 + quad * 8]);
  asm volatile("" : "+v"(aq[0][0]), "+v"(aq[0][1]), "+v"(aq[0][2]), "+v"(aq[0][3]),
                    "+v"(aq[1][0]), "+v"(aq[1][1]), "+v"(aq[1][2]), "+v"(aq[1][3]) :: "memory");

  // staging source pointers (swizzle keys constant across the i-unroll)
  const int srow = tid >> 4;                       // K: s-local row 0..15 (+16i)
  const int kswz = (tid & 15) ^ (srow & 7);
  const unsigned short* kgp = kp + ((size_t)bh << 11) * 128 + (size_t)srow * 128 + kswz * 8;
  const int dvrow = tid >> 3;                      // V: d-local row 0..31 (+32i)
  const int vswz = (tid & 7) ^ (dvrow & 7);
  const unsigned short* vgp = vtp + ((size_t)bh * 128 + dvrow) * SS + vswz * 8;

  auto STG = [&](int buf, int kb) {
    #pragma unroll
    for (int i = 0; i < 4; i++)
      gl_lds16(kgp + ((size_t)kb + i * 16) * 128, &k_s[buf][(i * 256 + tid) * 8]);
    #pragma unroll
    for (int i = 0; i < 4; i++)
      gl_lds16(vgp + (size_t)kb + (size_t)i * 32 * SS, &vt_s[buf][(i * 256 + tid) * 8]);
  };

  float m_i[2][4], l_i[2][4];
  #pragma unroll
  for (int s = 0; s < 2; s++)
    #pragma unroll
    for (int r = 0; r < 4; r++) { m_i[s][r] = -1e30f; l_i[s][r] = 0.f; }
  f32x4 o[2][8];
  #pragma unroll
  for (int s = 0; s < 2; s++)
    #pragma unroll
    for (int dj = 0; dj < 8; dj++) o[s][dj] = (f32x4){0.f, 0.f, 0.f, 0.f};

  if (nkt > 0) STG(0, 0);

  for (int kt = 0; kt < nkt; kt++) {
    const int cur = kt & 1;
    const int kb = kt * 64;
    if (kt + 1 < nkt) {
      STG(cur ^ 1, kb + 64);                           // prefetch next tile
      asm volatile("s_waitcnt vmcnt(8)" ::: "memory"); // tile kt landed; kt+1 in flight
    } else {
      asm volatile("s_waitcnt vmcnt(0)" ::: "memory");
    }
    __builtin_amdgcn_s_barrier();   // tile kt resident block-wide

    #pragma unroll
    for (int s = 0; s < 2; s++) {
      if (kb <= wkx[s]) {   // wave-uniform causal early-out per strip
        // S = Q K^T
        f32x4 sa[4];
        #pragma unroll
        for (int j = 0; j < 4; j++) {
          sa[j] = (f32x4){0.f, 0.f, 0.f, 0.f};
          #pragma unroll
          for (int ks = 0; ks < 4; ks++) {
            bf16x8 bk = ldfrag(&k_s[cur][((j * 16 + c) << 7) + (((ks * 4 + quad) ^ (c & 7)) << 3)]);
            sa[j] = __builtin_amdgcn_mfma_f32_16x16x32_bf16(aq[s][ks], bk, sa[j], 0, 0, 0);
          }
        }

        // online softmax, base-2 (Q pre-scaled by 1/sqrt(DH)*log2e)
        float mt[4] = {-1e30f, -1e30f, -1e30f, -1e30f};
        if (kb + 63 <= kmn[s]) {       // fully visible tile: no masking
          #pragma unroll
          for (int j = 0; j < 4; j++)
            #pragma unroll
            for (int r = 0; r < 4; r++) mt[r] = fmaxf(mt[r], sa[j][r]);
        } else {
          #pragma unroll
          for (int j = 0; j < 4; j++) {
            int key = kb + j * 16 + c;
            #pragma unroll
            for (int r = 0; r < 4; r++) {
              float v = (key <= km[s][r]) ? sa[j][r] : -1e30f;
              sa[j][r] = v;
              mt[r] = fmaxf(mt[r], v);
            }
          }
        }
        float al[4], rs[4];
        #pragma unroll
        for (int r = 0; r < 4; r++) {
          mt[r] = rmax16(mt[r]);
          float mn = fmaxf(m_i[s][r], mt[r]);
          al[r] = __builtin_exp2f(m_i[s][r] - mn);
          m_i[s][r] = mn;
          rs[r] = 0.f;
        }
        #pragma unroll
        for (int j = 0; j < 4; j++)
          #pragma unroll
          for (int r = 0; r < 4; r++) {
            float pv = __builtin_exp2f(sa[j][r] - m_i[s][r]);
            sa[j][r] = pv;
            rs[r] += pv;
          }
        #pragma unroll
        for (int r = 0; r < 4; r++) {
          rs[r] = radd16(rs[r]);
          l_i[s][r] = l_i[s][r] * al[r] + rs[r];
        }
        #pragma unroll
        for (int dj = 0; dj < 8; dj++)
          #pragma unroll
          for (int r = 0; r < 4; r++) o[s][dj][r] *= al[r];

        // P: C-layout -> LDS -> A-layout (per-wave region, strip-sequential)
        #pragma unroll
        for (int j = 0; j < 4; j++)
          #pragma unroll
          for (int r = 0; r < 4; r++)
            p_s[w * 1152 + (quad * 4 + r) * 72 + j * 16 + c] = f2bf(sa[j][r]);

        #pragma unroll
        for (int ks2 = 0; ks2 < 2; ks2++) {
          bf16x8 ap = ldfrag(&p_s[w * 1152 + c * 72 + ks2 * 32 + quad * 8]);
          #pragma unroll
          for (int dj = 0; dj < 8; dj++) {
            bf16x8 bv = ldfrag(&vt_s[cur][((dj * 16 + c) << 6) + (((ks2 * 4 + quad) ^ (c & 7)) << 3)]);
            o[s][dj] = __builtin_amdgcn_mfma_f32_16x16x32_bf16(ap, bv, o[s][dj], 0, 0, 0);
          }
        }
      }
    }
    __builtin_amdgcn_s_barrier();   // all reads of buf[cur] done before overwrite
  }

  #pragma unroll
  for (int s = 0; s < 2; s++)
    #pragma unroll
    for (int r = 0; r < 4; r++) {
      int l = qbase + s * 64 + w * 16 + quad * 4 + r;
      bool ok = (l < nb);
      float inv = ok ? (1.0f / l_i[s][r]) : 0.0f;
      #pragma unroll
      for (int dj = 0; dj < 8; dj++)
        ctx[(((size_t)b << 10) + l) * (size_t)DD + h * 128 + dj * 16 + c] =
            f2bf(ok ? o[s][dj][r] * inv : 0.0f);
    }
}

// ---------------------------------------------------------------------------
extern "C" void kernel_launch(void* const* d_in, const int* in_sizes, int n_in,
                              void* d_out, int out_size, void* d_ws, size_t ws_size,
                              hipStream_t stream) {
  const float* q_src = (const float*)d_in[0];
  const float* k_src = (const float*)d_in[1];
  const float* v_src = (const float*)d_in[2];
  const float* Wq = (const float*)d_in[3];
  const float* Wk = (const float*)d_in[4];
  const float* Wv = (const float*)d_in[5];
  const float* Wo = (const float*)d_in[6];
  const int* skip = (const int*)d_in[9];

  char* p = (char*)d_ws;
  auto alloc = [&](size_t bytes) -> char* {
    char* r = p;
    p += (bytes + 255) & ~(size_t)255;
    return r;
  };
  unsigned short* a_q  = (unsigned short*)alloc((size_t)BB * MAXL * DD * 2);
  unsigned short* a_k  = (unsigned short*)alloc((size_t)BB * SS * DD * 2);
  unsigned short* a_v  = (unsigned short*)alloc((size_t)BB * SS * DD * 2);
  unsigned short* wt_q = (unsigned short*)alloc((size_t)DD * DD * 2);
  unsigned short* wt_k = (unsigned short*)alloc((size_t)DD * DD * 2);
  unsigned short* wt_v = (unsigned short*)alloc((size_t)DD * DD * 2);
  unsigned short* wt_o = (unsigned short*)alloc((size_t)DD * DD * 2);
  unsigned short* q_pro = (unsigned short*)alloc((size_t)BB * HH * MAXL * DHD * 2);
  unsigned short* k_pro = (unsigned short*)alloc((size_t)BB * HH * SS * DHD * 2);
  unsigned short* v_t   = (unsigned short*)alloc((size_t)BB * HH * SS * DHD * 2);
  int* posk = (int*)alloc((size_t)BB * MAXL * 4);
  int* nval = (int*)alloc(64);
  unsigned short* ctx = a_q;  // a_q dead after Q projection

  prep<<<NCVT + NTW + BB, 256, 0, stream>>>(q_src, k_src, v_src, a_q, a_k, a_v,
                                            Wq, Wk, Wv, Wo, wt_q, wt_k, wt_v, wt_o,
                                            skip, posk, nval);

  gemm8<128><<<dim3(8, 32), 512, 0, stream>>>(a_q, wt_q, q_pro, BB * MAXL, DD, DD, 0, 10);
  gemm8<256><<<dim3(8, 32), 512, 0, stream>>>(a_k, wt_k, k_pro, BB * SS, DD, DD, 0, 11);
  gemm8<256><<<dim3(8, 32), 512, 0, stream>>>(a_v, wt_v, v_t, BB * SS, DD, DD, 2, 11);

  rope2<<<(BB * HH * (MAXL + SS) * 64) / 256, 256, 0, stream>>>(q_pro, k_pro, posk);

  attn_kernel<<<dim3(BB * HH, MAXL / 128), 256, 0, stream>>>(q_pro, k_pro, v_t, posk, nval, ctx);

  gemm8<128><<<dim3(8, 32), 512, 0, stream>>>(ctx, wt_o, d_out, BB * MAXL, DD, DD, 1, 0);
}